// Round 22
// baseline (140.179 us; speedup 1.0000x reference)
//
#include <hip/hip_runtime.h>

#define S_LEN 16
#define NMODEL 4096
#define DHEAD 128
#define HHEADS 32
#define MCACHE 8192
#define SPLITK 32
#define KSLICE (NMODEL / SPLITK)   // 128
#define CHUNK_W 64                 // rows per WAVE (r13 proven)
#define NCHT (MCACHE / CHUNK_W)    // 128 chunks per head
#define MPAD 68                    // scs[s][m] row stride: 272 B, 16B-aligned

#define PART_ELEMS   ((size_t)3 * SPLITK * S_LEN * NMODEL)        // 6.29M floats
#define OPART_USH    ((size_t)HHEADS * NCHT * S_LEN * DHEAD)      // 8.39M ushorts
#define OPART_FLOATS (OPART_USH / 2)                              // 4.19M floats
#define REGION_ELEMS (PART_ELEMS > OPART_FLOATS ? PART_ELEMS : OPART_FLOATS)
#define STAT_ELEMS   ((size_t)HHEADS * NCHT * S_LEN)              // 65536

typedef _Float16 half8 __attribute__((ext_vector_type(8)));
typedef float    f32x4 __attribute__((ext_vector_type(4)));

__device__ __forceinline__ half8 cvt8(float4 a, float4 b) {
    half8 h;
    h[0] = (_Float16)a.x; h[1] = (_Float16)a.y; h[2] = (_Float16)a.z; h[3] = (_Float16)a.w;
    h[4] = (_Float16)b.x; h[5] = (_Float16)b.y; h[6] = (_Float16)b.z; h[7] = (_Float16)b.w;
    return h;
}
__device__ __forceinline__ unsigned short f2h(float f) {
    _Float16 h = (_Float16)f; unsigned short u; __builtin_memcpy(&u, &h, 2); return u;
}
__device__ __forceinline__ float h2f(unsigned short u) {
    _Float16 h; __builtin_memcpy(&h, &u, 2); return (float)h;
}

// ---------------- Kernel 1: split-K partial QKV projection ----------------
// grid (8,32,3), block 256. 2-stage pipeline (r19 proven).
__global__ __launch_bounds__(256) void qkv_gemm(const float* __restrict__ X,
                                                const float* __restrict__ Wq,
                                                const float* __restrict__ Wk,
                                                const float* __restrict__ Wv,
                                                float* __restrict__ part) {
    const int tid   = threadIdx.x;
    const int col2  = blockIdx.x * 256 + tid;
    const int split = blockIdx.y;
    const int mat   = blockIdx.z;
    const float* __restrict__ W = (mat == 0) ? Wq : (mat == 1) ? Wk : Wv;
    const int k0 = split * KSLICE;

    __shared__ float Xs[KSLICE][S_LEN];     // 8 KB
    for (int i = tid; i < KSLICE * S_LEN; i += 256) {
        const int s = i & 15, k = i >> 4;
        Xs[k][s] = X[s * NMODEL + k0 + k];
    }
    __syncthreads();

    float2 acc[S_LEN];
#pragma unroll
    for (int s = 0; s < S_LEN; ++s) { acc[s].x = 0.f; acc[s].y = 0.f; }

    const float2* __restrict__ Wp = (const float2*)(W + (size_t)k0 * NMODEL) + col2;

    float2 bufA[8];
#pragma unroll
    for (int u = 0; u < 8; ++u) bufA[u] = Wp[(size_t)u * (NMODEL / 2)];

#pragma unroll 1
    for (int kb = 0; kb < KSLICE - 8; kb += 8) {
        float2 bufB[8];
#pragma unroll
        for (int u = 0; u < 8; ++u)
            bufB[u] = Wp[(size_t)(kb + 8 + u) * (NMODEL / 2)];
#pragma unroll
        for (int u = 0; u < 8; ++u) {
            const float2 w = bufA[u];
            const float4* __restrict__ xr = (const float4*)&Xs[kb + u][0];
#pragma unroll
            for (int s4 = 0; s4 < 4; ++s4) {
                const float4 xv = xr[s4];
                acc[s4 * 4 + 0].x += xv.x * w.x;  acc[s4 * 4 + 0].y += xv.x * w.y;
                acc[s4 * 4 + 1].x += xv.y * w.x;  acc[s4 * 4 + 1].y += xv.y * w.y;
                acc[s4 * 4 + 2].x += xv.z * w.x;  acc[s4 * 4 + 2].y += xv.z * w.y;
                acc[s4 * 4 + 3].x += xv.w * w.x;  acc[s4 * 4 + 3].y += xv.w * w.y;
            }
        }
#pragma unroll
        for (int u = 0; u < 8; ++u) bufA[u] = bufB[u];
    }
#pragma unroll
    for (int u = 0; u < 8; ++u) {
        const float2 w = bufA[u];
        const float4* __restrict__ xr = (const float4*)&Xs[KSLICE - 8 + u][0];
#pragma unroll
        for (int s4 = 0; s4 < 4; ++s4) {
            const float4 xv = xr[s4];
            acc[s4 * 4 + 0].x += xv.x * w.x;  acc[s4 * 4 + 0].y += xv.x * w.y;
            acc[s4 * 4 + 1].x += xv.y * w.x;  acc[s4 * 4 + 1].y += xv.y * w.y;
            acc[s4 * 4 + 2].x += xv.z * w.x;  acc[s4 * 4 + 2].y += xv.z * w.y;
            acc[s4 * 4 + 3].x += xv.w * w.x;  acc[s4 * 4 + 3].y += xv.w * w.y;
        }
    }

    float2* __restrict__ pp =
        (float2*)(part + (size_t)(mat * SPLITK + split) * S_LEN * NMODEL) + col2;
#pragma unroll
    for (int s = 0; s < S_LEN; ++s) pp[(size_t)s * (NMODEL / 2)] = acc[s];
}

// ---------------- Kernel 2: reduce split-K partials ----------------
__global__ __launch_bounds__(256) void qkv_reduce(const float* __restrict__ part,
                                                  float* __restrict__ qkv) {
    const int i4   = blockIdx.x * 256 + threadIdx.x;
    const int flat = i4 * 4;
    const int mat  = flat / (S_LEN * NMODEL);
    const int rem  = flat % (S_LEN * NMODEL);
    float4 sum = {0.f, 0.f, 0.f, 0.f};
#pragma unroll 8
    for (int sp = 0; sp < SPLITK; ++sp) {
        const float4 v = *(const float4*)(part +
            (size_t)(mat * SPLITK + sp) * (S_LEN * NMODEL) + rem);
        sum.x += v.x; sum.y += v.y; sum.z += v.z; sum.w += v.w;
    }
    *(float4*)(qkv + flat) = sum;
}

// ---------------- Kernel 3: flash-decode, MFMA QK^T + pipelined VALU PV ----------------
// ONE WAVE PER BLOCK (r21) + phase-3 2-stage pipeline (r19, now isolated).
// Grid 16 waves/CU = 4/SIMD -> VGPR up to 128 is free occupancy-wise.
__global__ __launch_bounds__(64) void attn_partial(const float* __restrict__ qkv,
                                                   const float* __restrict__ cacheK,
                                                   const float* __restrict__ cacheV,
                                                   const int* __restrict__ Pp,
                                                   unsigned short* __restrict__ opart,
                                                   float* __restrict__ mstat,
                                                   float* __restrict__ lstat) {
    const int c    = blockIdx.x;
    const int h    = blockIdx.y;
    const int lane = threadIdx.x;            // 0..63
    const int c0   = c * CHUNK_W;
    const int P    = *Pp;
    const int lo   = (P > c0) ? P : c0;
    const int hi_  = (P + S_LEN < c0 + CHUNK_W) ? (P + S_LEN) : (c0 + CHUNK_W);
    const bool overlap = (lo < hi_);         // wave-uniform

    const float* qb = qkv;
    const float* kb = qkv + S_LEN * NMODEL;
    const float* vb = qkv + 2 * S_LEN * NMODEL;

    __shared__ float scs[S_LEN][MPAD];       // 4.3 KB, scores [s][m]
    __shared__ float ml[S_LEN], ll[S_LEN];

    const int row16 = lane & 15;
    const int kg    = lane >> 4;

    // ---- phase 1: QK^T via MFMA (4 row-tiles x 4 k-slices) ----
    {
        half8 qf[4];
#pragma unroll
        for (int cs = 0; cs < 4; ++cs) {
            const float* qr = qb + row16 * NMODEL + h * DHEAD + cs * 32 + kg * 8;
            qf[cs] = cvt8(*(const float4*)qr, *(const float4*)(qr + 4));
        }
#pragma unroll
        for (int t = 0; t < 4; ++t) {
            const float* krow = cacheK +
                ((size_t)h * MCACHE + c0 + t * 16 + row16) * DHEAD + kg * 8;
            float4 ka[4], kc[4];
#pragma unroll
            for (int cs = 0; cs < 4; ++cs) {           // hoist: 8 loads in flight
                ka[cs] = *(const float4*)(krow + cs * 32);
                kc[cs] = *(const float4*)(krow + cs * 32 + 4);
            }
            f32x4 acc = {0.f, 0.f, 0.f, 0.f};
#pragma unroll
            for (int cs = 0; cs < 4; ++cs)
                acc = __builtin_amdgcn_mfma_f32_16x16x32_f16(qf[cs], cvt8(ka[cs], kc[cs]),
                                                             acc, 0, 0, 0);
#pragma unroll
            for (int r = 0; r < 4; ++r)
                scs[kg * 4 + r][t * 16 + row16] = acc[r];
        }

        // fixup: recompute overlap rows' scores in exact fp32 with fresh k
        if (overlap) {
            const int sq = kg, dsl = row16, doff = dsl * 8;
            float4 q0[4], q1[4];
#pragma unroll
            for (int j = 0; j < 4; ++j) {
                const int s = sq * 4 + j;
                q0[j] = *(const float4*)(qb + s * NMODEL + h * DHEAD + doff);
                q1[j] = *(const float4*)(qb + s * NMODEL + h * DHEAD + doff + 4);
            }
            for (int gm = lo; gm < hi_; ++gm) {
                const float* kr = kb + (size_t)(gm - P) * NMODEL + h * DHEAD + doff;
                const float4 ka = *(const float4*)(kr);
                const float4 kc = *(const float4*)(kr + 4);
                float pr[4];
#pragma unroll
                for (int j = 0; j < 4; ++j) {
                    pr[j] = ka.x * q0[j].x + ka.y * q0[j].y + ka.z * q0[j].z + ka.w * q0[j].w
                          + kc.x * q1[j].x + kc.y * q1[j].y + kc.z * q1[j].z + kc.w * q1[j].w;
                }
#pragma unroll
                for (int j = 0; j < 4; ++j) {
                    float v = pr[j];
                    v += __shfl_xor(v, 1, 64);
                    v += __shfl_xor(v, 2, 64);
                    v += __shfl_xor(v, 4, 64);
                    v += __shfl_xor(v, 8, 64);
                    pr[j] = v;
                }
                if (dsl == 0) {
#pragma unroll
                    for (int j = 0; j < 4; ++j)
                        scs[sq * 4 + j][gm - c0] = pr[j];
                }
            }
        }
    }
    __syncthreads();

    // ---- phase 2: LANE-PARALLEL softmax stats (r17 proven) ----
    {
        const int s  = lane >> 2;
        const int mg = lane & 3;
        float4 v0 = *(const float4*)&scs[s][mg * 16];
        float4 v1 = *(const float4*)&scs[s][mg * 16 + 4];
        float4 v2 = *(const float4*)&scs[s][mg * 16 + 8];
        float4 v3 = *(const float4*)&scs[s][mg * 16 + 12];

        float mx = fmaxf(fmaxf(fmaxf(v0.x, v0.y), fmaxf(v0.z, v0.w)),
                         fmaxf(fmaxf(v1.x, v1.y), fmaxf(v1.z, v1.w)));
        mx = fmaxf(mx, fmaxf(fmaxf(fmaxf(v2.x, v2.y), fmaxf(v2.z, v2.w)),
                             fmaxf(fmaxf(v3.x, v3.y), fmaxf(v3.z, v3.w))));
        mx = fmaxf(mx, __shfl_xor(mx, 1, 64));
        mx = fmaxf(mx, __shfl_xor(mx, 2, 64));

        v0.x = __expf(v0.x - mx); v0.y = __expf(v0.y - mx);
        v0.z = __expf(v0.z - mx); v0.w = __expf(v0.w - mx);
        v1.x = __expf(v1.x - mx); v1.y = __expf(v1.y - mx);
        v1.z = __expf(v1.z - mx); v1.w = __expf(v1.w - mx);
        v2.x = __expf(v2.x - mx); v2.y = __expf(v2.y - mx);
        v2.z = __expf(v2.z - mx); v2.w = __expf(v2.w - mx);
        v3.x = __expf(v3.x - mx); v3.y = __expf(v3.y - mx);
        v3.z = __expf(v3.z - mx); v3.w = __expf(v3.w - mx);

        float sum = (v0.x + v0.y + v0.z + v0.w) + (v1.x + v1.y + v1.z + v1.w)
                  + (v2.x + v2.y + v2.z + v2.w) + (v3.x + v3.y + v3.z + v3.w);
        sum += __shfl_xor(sum, 1, 64);
        sum += __shfl_xor(sum, 2, 64);

        *(float4*)&scs[s][mg * 16]      = v0;
        *(float4*)&scs[s][mg * 16 + 4]  = v1;
        *(float4*)&scs[s][mg * 16 + 8]  = v2;
        *(float4*)&scs[s][mg * 16 + 12] = v3;

        if (mg == 0) { ml[s] = mx; ll[s] = sum; }
    }
    __syncthreads();

    // ---- phase 3: pipelined PV. 4-row blocks; vA/vB 2-stage; float4 p-reads ----
    {
        const int sq = lane >> 4, dsl = lane & 15, doff = dsl * 8;
        const float* vbase = cacheV + ((size_t)h * MCACHE + c0) * DHEAD + doff;
        float a[4][8];
#pragma unroll
        for (int j = 0; j < 4; ++j)
#pragma unroll
            for (int k = 0; k < 8; ++k) a[j][k] = 0.f;

        float4 vA[8];
#pragma unroll
        for (int i = 0; i < 4; ++i) {
            vA[2 * i]     = *(const float4*)(vbase + (size_t)i * DHEAD);
            vA[2 * i + 1] = *(const float4*)(vbase + (size_t)i * DHEAD + 4);
        }

#pragma unroll 1
        for (int mb = 0; mb < CHUNK_W - 4; mb += 4) {
            float4 vB[8];
#pragma unroll
            for (int i = 0; i < 4; ++i) {
                vB[2 * i]     = *(const float4*)(vbase + (size_t)(mb + 4 + i) * DHEAD);
                vB[2 * i + 1] = *(const float4*)(vbase + (size_t)(mb + 4 + i) * DHEAD + 4);
            }
            float4 p4[4];
#pragma unroll
            for (int j = 0; j < 4; ++j)
                p4[j] = *(const float4*)&scs[sq * 4 + j][mb];
#pragma unroll
            for (int i = 0; i < 4; ++i) {
#pragma unroll
                for (int j = 0; j < 4; ++j) {
                    const float p = (i == 0) ? p4[j].x : (i == 1) ? p4[j].y
                                  : (i == 2) ? p4[j].z : p4[j].w;
                    a[j][0] += p * vA[2 * i].x; a[j][1] += p * vA[2 * i].y;
                    a[j][2] += p * vA[2 * i].z; a[j][3] += p * vA[2 * i].w;
                    a[j][4] += p * vA[2 * i + 1].x; a[j][5] += p * vA[2 * i + 1].y;
                    a[j][6] += p * vA[2 * i + 1].z; a[j][7] += p * vA[2 * i + 1].w;
                }
            }
#pragma unroll
            for (int u = 0; u < 8; ++u) vA[u] = vB[u];
        }
        {   // peeled final block
            const int mb = CHUNK_W - 4;
            float4 p4[4];
#pragma unroll
            for (int j = 0; j < 4; ++j)
                p4[j] = *(const float4*)&scs[sq * 4 + j][mb];
#pragma unroll
            for (int i = 0; i < 4; ++i) {
#pragma unroll
                for (int j = 0; j < 4; ++j) {
                    const float p = (i == 0) ? p4[j].x : (i == 1) ? p4[j].y
                                  : (i == 2) ? p4[j].z : p4[j].w;
                    a[j][0] += p * vA[2 * i].x; a[j][1] += p * vA[2 * i].y;
                    a[j][2] += p * vA[2 * i].z; a[j][3] += p * vA[2 * i].w;
                    a[j][4] += p * vA[2 * i + 1].x; a[j][5] += p * vA[2 * i + 1].y;
                    a[j][6] += p * vA[2 * i + 1].z; a[j][7] += p * vA[2 * i + 1].w;
                }
            }
        }

        if (overlap) {                        // stale-V correction: p*(Vnew-Vold)
            for (int gm = lo; gm < hi_; ++gm) {
                const int i = gm - c0;
                const float pj[4] = {scs[sq * 4 + 0][i], scs[sq * 4 + 1][i],
                                     scs[sq * 4 + 2][i], scs[sq * 4 + 3][i]};
                const float* vn = vb + (size_t)(gm - P) * NMODEL + h * DHEAD + doff;
                const float* vo = cacheV + ((size_t)h * MCACHE + gm) * DHEAD + doff;
                const float4 n0 = *(const float4*)(vn);
                const float4 n1 = *(const float4*)(vn + 4);
                const float4 o0 = *(const float4*)(vo);
                const float4 o1 = *(const float4*)(vo + 4);
#pragma unroll
                for (int j = 0; j < 4; ++j) {
                    a[j][0] += pj[j] * (n0.x - o0.x); a[j][1] += pj[j] * (n0.y - o0.y);
                    a[j][2] += pj[j] * (n0.z - o0.z); a[j][3] += pj[j] * (n0.w - o0.w);
                    a[j][4] += pj[j] * (n1.x - o1.x); a[j][5] += pj[j] * (n1.y - o1.y);
                    a[j][6] += pj[j] * (n1.z - o1.z); a[j][7] += pj[j] * (n1.w - o1.w);
                }
            }
        }

        const size_t ob = ((size_t)h * NCHT + c) * S_LEN * DHEAD;
#pragma unroll
        for (int j = 0; j < 4; ++j) {
            const int s = sq * 4 + j;
            uint4 pk;
            unsigned short* us = (unsigned short*)&pk;
#pragma unroll
            for (int k = 0; k < 8; ++k) us[k] = f2h(a[j][k]);
            *(uint4*)&opart[ob + (size_t)s * DHEAD + doff] = pk;
        }
    }

    if (lane < S_LEN) {
        mstat[((size_t)h * S_LEN + lane) * NCHT + c] = ml[lane];
        lstat[((size_t)h * S_LEN + lane) * NCHT + c] = ll[lane];
    }
}

// ---------------- Kernel 4: combine (coalesced d-pair loads) ----------------
__global__ __launch_bounds__(512) void attn_combine(const unsigned short* __restrict__ opart,
                                                    const float* __restrict__ mstat,
                                                    const float* __restrict__ lstat,
                                                    float* __restrict__ out) {
    const int tid = threadIdx.x;
    const int dp  = tid & 63;        // d-pair: d = 2*dp, 2*dp+1
    const int cg  = tid >> 6;        // 0..7
    const int s   = blockIdx.x;
    const int h   = blockIdx.y;

    __shared__ float mlds[NCHT], llds[NCHT], wlds[NCHT];
    __shared__ float olds[8][DHEAD];
    __shared__ float Llds[8];

    const size_t sb = ((size_t)h * S_LEN + s) * NCHT;
    if (tid < NCHT) { mlds[tid] = mstat[sb + tid]; llds[tid] = lstat[sb + tid]; }
    __syncthreads();

    float gmax = fmaxf(mlds[tid & 63], mlds[(tid & 63) + 64]);
    for (int off = 32; off > 0; off >>= 1) gmax = fmaxf(gmax, __shfl_xor(gmax, off, 64));

    if (tid < NCHT) wlds[tid] = __expf(mlds[tid] - gmax);
    __syncthreads();

    float ox = 0.f, oy = 0.f, L = 0.f;
    for (int c = cg; c < NCHT; c += 8) {
        const float w = wlds[c];
        const unsigned int u = *(const unsigned int*)
            &opart[(((size_t)h * NCHT + c) * S_LEN + s) * DHEAD + dp * 2];
        ox += w * h2f((unsigned short)(u & 0xffffu));
        oy += w * h2f((unsigned short)(u >> 16));
        L  += w * llds[c];
    }
    olds[cg][dp * 2]     = ox;
    olds[cg][dp * 2 + 1] = oy;
    if (dp == 0) Llds[cg] = L;
    __syncthreads();

    if (tid < DHEAD) {
        float ot = 0.f, Lt = 0.f;
#pragma unroll
        for (int g = 0; g < 8; ++g) { ot += olds[g][tid]; Lt += Llds[g]; }
        out[((size_t)h * S_LEN + s) * DHEAD + tid] = ot / Lt;
    }
}

extern "C" void kernel_launch(void* const* d_in, const int* in_sizes, int n_in,
                              void* d_out, int out_size, void* d_ws, size_t ws_size,
                              hipStream_t stream) {
    const float* X      = (const float*)d_in[0];
    const float* Wq     = (const float*)d_in[1];
    const float* Wk     = (const float*)d_in[2];
    const float* Wv     = (const float*)d_in[3];
    const float* cacheK = (const float*)d_in[4];
    const float* cacheV = (const float*)d_in[5];
    const int*   P      = (const int*)d_in[6];
    float* out = (float*)d_out;
    float* ws  = (float*)d_ws;

    float*          qkv   = ws;                                  // 196608 floats
    float*          part  = qkv + 3 * S_LEN * NMODEL;
    unsigned short* opart = (unsigned short*)part;               // aliases part
    float*          mstat = part + REGION_ELEMS;
    float*          lstat = mstat + STAT_ELEMS;

    qkv_gemm<<<dim3(8, SPLITK, 3), 256, 0, stream>>>(X, Wq, Wk, Wv, part);
    qkv_reduce<<<(3 * S_LEN * NMODEL / 4) / 256, 256, 0, stream>>>(part, qkv);
    attn_partial<<<dim3(NCHT, HHEADS), 64, 0, stream>>>(qkv, cacheK, cacheV, P,
                                                        opart, mstat, lstat);
    attn_combine<<<dim3(S_LEN, HHEADS), 512, 0, stream>>>(opart, mstat, lstat, out);
}

// Round 23
// 130.351 us; speedup vs baseline: 1.0754x; 1.0754x over previous
//
#include <hip/hip_runtime.h>

#define S_LEN 16
#define NMODEL 4096
#define DHEAD 128
#define HHEADS 32
#define MCACHE 8192
#define SPLITK 32
#define KSLICE (NMODEL / SPLITK)   // 128
#define CHUNK_W 64                 // rows per WAVE (r13 proven)
#define NCHT (MCACHE / CHUNK_W)    // 128 chunks per head
#define MPAD 68                    // scs[s][m] row stride: 272 B, 16B-aligned

#define PART_ELEMS   ((size_t)3 * SPLITK * S_LEN * NMODEL)        // 6.29M floats
#define OPART_USH    ((size_t)HHEADS * NCHT * S_LEN * DHEAD)      // 8.39M ushorts
#define OPART_FLOATS (OPART_USH / 2)                              // 4.19M floats
#define REGION_ELEMS (PART_ELEMS > OPART_FLOATS ? PART_ELEMS : OPART_FLOATS)
#define STAT_ELEMS   ((size_t)HHEADS * NCHT * S_LEN)              // 65536

typedef _Float16 half8 __attribute__((ext_vector_type(8)));
typedef float    f32x4 __attribute__((ext_vector_type(4)));

__device__ __forceinline__ half8 cvt8(float4 a, float4 b) {
    half8 h;
    h[0] = (_Float16)a.x; h[1] = (_Float16)a.y; h[2] = (_Float16)a.z; h[3] = (_Float16)a.w;
    h[4] = (_Float16)b.x; h[5] = (_Float16)b.y; h[6] = (_Float16)b.z; h[7] = (_Float16)b.w;
    return h;
}
__device__ __forceinline__ unsigned short f2h(float f) {
    _Float16 h = (_Float16)f; unsigned short u; __builtin_memcpy(&u, &h, 2); return u;
}
__device__ __forceinline__ float h2f(unsigned short u) {
    _Float16 h; __builtin_memcpy(&h, &u, 2); return (float)h;
}

// ---------------- Kernel 1: split-K partial QKV projection ----------------
// grid (8,32,3), block 256. wbuf staging (r18-measured best total config).
__global__ __launch_bounds__(256) void qkv_gemm(const float* __restrict__ X,
                                                const float* __restrict__ Wq,
                                                const float* __restrict__ Wk,
                                                const float* __restrict__ Wv,
                                                float* __restrict__ part) {
    const int tid   = threadIdx.x;
    const int col2  = blockIdx.x * 256 + tid;
    const int split = blockIdx.y;
    const int mat   = blockIdx.z;
    const float* __restrict__ W = (mat == 0) ? Wq : (mat == 1) ? Wk : Wv;
    const int k0 = split * KSLICE;

    __shared__ float Xs[KSLICE][S_LEN];     // 8 KB
    for (int i = tid; i < KSLICE * S_LEN; i += 256) {
        const int s = i & 15, k = i >> 4;
        Xs[k][s] = X[s * NMODEL + k0 + k];
    }
    __syncthreads();

    float2 acc[S_LEN];
#pragma unroll
    for (int s = 0; s < S_LEN; ++s) { acc[s].x = 0.f; acc[s].y = 0.f; }

    const float2* __restrict__ Wp = (const float2*)(W + (size_t)k0 * NMODEL) + col2;

#pragma unroll 1
    for (int kb = 0; kb < KSLICE; kb += 8) {
        float2 wbuf[8];
#pragma unroll
        for (int u = 0; u < 8; ++u)
            wbuf[u] = Wp[(size_t)(kb + u) * (NMODEL / 2)];
#pragma unroll
        for (int u = 0; u < 8; ++u) {
            const float2 w = wbuf[u];
            const float4* __restrict__ xr = (const float4*)&Xs[kb + u][0];
#pragma unroll
            for (int s4 = 0; s4 < 4; ++s4) {
                const float4 xv = xr[s4];
                acc[s4 * 4 + 0].x += xv.x * w.x;  acc[s4 * 4 + 0].y += xv.x * w.y;
                acc[s4 * 4 + 1].x += xv.y * w.x;  acc[s4 * 4 + 1].y += xv.y * w.y;
                acc[s4 * 4 + 2].x += xv.z * w.x;  acc[s4 * 4 + 2].y += xv.z * w.y;
                acc[s4 * 4 + 3].x += xv.w * w.x;  acc[s4 * 4 + 3].y += xv.w * w.y;
            }
        }
    }

    float2* __restrict__ pp =
        (float2*)(part + (size_t)(mat * SPLITK + split) * S_LEN * NMODEL) + col2;
#pragma unroll
    for (int s = 0; s < S_LEN; ++s) pp[(size_t)s * (NMODEL / 2)] = acc[s];
}

// ---------------- Kernel 2: reduce split-K partials ----------------
__global__ __launch_bounds__(256) void qkv_reduce(const float* __restrict__ part,
                                                  float* __restrict__ qkv) {
    const int i4   = blockIdx.x * 256 + threadIdx.x;
    const int flat = i4 * 4;
    const int mat  = flat / (S_LEN * NMODEL);
    const int rem  = flat % (S_LEN * NMODEL);
    float4 sum = {0.f, 0.f, 0.f, 0.f};
#pragma unroll 8
    for (int sp = 0; sp < SPLITK; ++sp) {
        const float4 v = *(const float4*)(part +
            (size_t)(mat * SPLITK + sp) * (S_LEN * NMODEL) + rem);
        sum.x += v.x; sum.y += v.y; sum.z += v.z; sum.w += v.w;
    }
    *(float4*)(qkv + flat) = sum;
}

// ---------------- Kernel 3: flash-decode, MFMA QK^T + VALU PV ----------------
// r13 structure + lane-parallel phase 2 (r17/r18-measured best).
// grid = (NCHT/2=64, HHEADS=32), block 128 (2 waves, wave owns a 64-row chunk).
__global__ __launch_bounds__(128) void attn_partial(const float* __restrict__ qkv,
                                                    const float* __restrict__ cacheK,
                                                    const float* __restrict__ cacheV,
                                                    const int* __restrict__ Pp,
                                                    unsigned short* __restrict__ opart,
                                                    float* __restrict__ mstat,
                                                    float* __restrict__ lstat) {
    const int bx   = blockIdx.x;
    const int h    = blockIdx.y;
    const int tid  = threadIdx.x;
    const int wv   = tid >> 6;
    const int lane = tid & 63;
    const int c    = bx * 2 + wv;
    const int c0   = c * CHUNK_W;
    const int P    = *Pp;
    const int lo   = (P > c0) ? P : c0;
    const int hi_  = (P + S_LEN < c0 + CHUNK_W) ? (P + S_LEN) : (c0 + CHUNK_W);
    const bool overlap = (lo < hi_);         // wave-uniform

    const float* qb = qkv;
    const float* kb = qkv + S_LEN * NMODEL;
    const float* vb = qkv + 2 * S_LEN * NMODEL;

    __shared__ float scs[2][S_LEN][MPAD];    // 8.5 KB, scores [s][m]
    __shared__ float ml[2][S_LEN], ll[2][S_LEN];

    const int row16 = lane & 15;
    const int kg    = lane >> 4;

    // ---- phase 1: QK^T via MFMA (4 row-tiles x 4 k-slices) ----
    {
        half8 qf[4];
#pragma unroll
        for (int cs = 0; cs < 4; ++cs) {
            const float* qr = qb + row16 * NMODEL + h * DHEAD + cs * 32 + kg * 8;
            qf[cs] = cvt8(*(const float4*)qr, *(const float4*)(qr + 4));
        }
#pragma unroll
        for (int t = 0; t < 4; ++t) {
            const float* krow = cacheK +
                ((size_t)h * MCACHE + c0 + t * 16 + row16) * DHEAD + kg * 8;
            f32x4 acc = {0.f, 0.f, 0.f, 0.f};
#pragma unroll
            for (int cs = 0; cs < 4; ++cs) {
                const float4 ka = *(const float4*)(krow + cs * 32);
                const float4 kc = *(const float4*)(krow + cs * 32 + 4);
                acc = __builtin_amdgcn_mfma_f32_16x16x32_f16(qf[cs], cvt8(ka, kc),
                                                             acc, 0, 0, 0);
            }
            // D: lane -> S[s = kg*4 + r][m = t*16 + row16]
#pragma unroll
            for (int r = 0; r < 4; ++r)
                scs[wv][kg * 4 + r][t * 16 + row16] = acc[r];
        }

        // fixup: recompute overlap rows' scores in exact fp32 with fresh k
        if (overlap) {
            const int sq = kg, dsl = row16, doff = dsl * 8;
            float4 q0[4], q1[4];
#pragma unroll
            for (int j = 0; j < 4; ++j) {
                const int s = sq * 4 + j;
                q0[j] = *(const float4*)(qb + s * NMODEL + h * DHEAD + doff);
                q1[j] = *(const float4*)(qb + s * NMODEL + h * DHEAD + doff + 4);
            }
            for (int gm = lo; gm < hi_; ++gm) {
                const float* kr = kb + (size_t)(gm - P) * NMODEL + h * DHEAD + doff;
                const float4 ka = *(const float4*)(kr);
                const float4 kc = *(const float4*)(kr + 4);
                float pr[4];
#pragma unroll
                for (int j = 0; j < 4; ++j) {
                    pr[j] = ka.x * q0[j].x + ka.y * q0[j].y + ka.z * q0[j].z + ka.w * q0[j].w
                          + kc.x * q1[j].x + kc.y * q1[j].y + kc.z * q1[j].z + kc.w * q1[j].w;
                }
#pragma unroll
                for (int j = 0; j < 4; ++j) {
                    float v = pr[j];
                    v += __shfl_xor(v, 1, 64);
                    v += __shfl_xor(v, 2, 64);
                    v += __shfl_xor(v, 4, 64);
                    v += __shfl_xor(v, 8, 64);
                    pr[j] = v;
                }
                if (dsl == 0) {
#pragma unroll
                    for (int j = 0; j < 4; ++j)
                        scs[wv][sq * 4 + j][gm - c0] = pr[j];
                }
            }
        }
    }
    __syncthreads();

    // ---- phase 2: LANE-PARALLEL softmax stats. lane = (s = lane>>2, mg = lane&3)
    {
        const int s  = lane >> 2;
        const int mg = lane & 3;
        float4 v0 = *(const float4*)&scs[wv][s][mg * 16];
        float4 v1 = *(const float4*)&scs[wv][s][mg * 16 + 4];
        float4 v2 = *(const float4*)&scs[wv][s][mg * 16 + 8];
        float4 v3 = *(const float4*)&scs[wv][s][mg * 16 + 12];

        float mx = fmaxf(fmaxf(fmaxf(v0.x, v0.y), fmaxf(v0.z, v0.w)),
                         fmaxf(fmaxf(v1.x, v1.y), fmaxf(v1.z, v1.w)));
        mx = fmaxf(mx, fmaxf(fmaxf(fmaxf(v2.x, v2.y), fmaxf(v2.z, v2.w)),
                             fmaxf(fmaxf(v3.x, v3.y), fmaxf(v3.z, v3.w))));
        mx = fmaxf(mx, __shfl_xor(mx, 1, 64));
        mx = fmaxf(mx, __shfl_xor(mx, 2, 64));

        v0.x = __expf(v0.x - mx); v0.y = __expf(v0.y - mx);
        v0.z = __expf(v0.z - mx); v0.w = __expf(v0.w - mx);
        v1.x = __expf(v1.x - mx); v1.y = __expf(v1.y - mx);
        v1.z = __expf(v1.z - mx); v1.w = __expf(v1.w - mx);
        v2.x = __expf(v2.x - mx); v2.y = __expf(v2.y - mx);
        v2.z = __expf(v2.z - mx); v2.w = __expf(v2.w - mx);
        v3.x = __expf(v3.x - mx); v3.y = __expf(v3.y - mx);
        v3.z = __expf(v3.z - mx); v3.w = __expf(v3.w - mx);

        float sum = (v0.x + v0.y + v0.z + v0.w) + (v1.x + v1.y + v1.z + v1.w)
                  + (v2.x + v2.y + v2.z + v2.w) + (v3.x + v3.y + v3.z + v3.w);
        sum += __shfl_xor(sum, 1, 64);
        sum += __shfl_xor(sum, 2, 64);

        *(float4*)&scs[wv][s][mg * 16]      = v0;
        *(float4*)&scs[wv][s][mg * 16 + 4]  = v1;
        *(float4*)&scs[wv][s][mg * 16 + 8]  = v2;
        *(float4*)&scs[wv][s][mg * 16 + 12] = v3;

        if (mg == 0) { ml[wv][s] = mx; ll[wv][s] = sum; }
    }
    __syncthreads();

    // ---- phase 3: o[s][d] partials; VALU PV, b128 V loads (r13 proven) ----
    {
        const int sq = lane >> 4, dsl = lane & 15, doff = dsl * 8;
        const float* vbase = cacheV + ((size_t)h * MCACHE + c0) * DHEAD + doff;
        float a[4][8];
#pragma unroll
        for (int j = 0; j < 4; ++j)
#pragma unroll
            for (int k = 0; k < 8; ++k) a[j][k] = 0.f;

        for (int m = 0; m < CHUNK_W; ++m) {
            const float pj[4] = {scs[wv][sq * 4 + 0][m], scs[wv][sq * 4 + 1][m],
                                 scs[wv][sq * 4 + 2][m], scs[wv][sq * 4 + 3][m]};
            const float4 v0 = *(const float4*)(vbase + (size_t)m * DHEAD);
            const float4 v1 = *(const float4*)(vbase + (size_t)m * DHEAD + 4);
#pragma unroll
            for (int j = 0; j < 4; ++j) {
                a[j][0] += pj[j] * v0.x; a[j][1] += pj[j] * v0.y;
                a[j][2] += pj[j] * v0.z; a[j][3] += pj[j] * v0.w;
                a[j][4] += pj[j] * v1.x; a[j][5] += pj[j] * v1.y;
                a[j][6] += pj[j] * v1.z; a[j][7] += pj[j] * v1.w;
            }
        }

        if (overlap) {                        // stale-V correction: p*(Vnew-Vold)
            for (int gm = lo; gm < hi_; ++gm) {
                const int i = gm - c0;
                const float pj[4] = {scs[wv][sq * 4 + 0][i], scs[wv][sq * 4 + 1][i],
                                     scs[wv][sq * 4 + 2][i], scs[wv][sq * 4 + 3][i]};
                const float* vn = vb + (size_t)(gm - P) * NMODEL + h * DHEAD + doff;
                const float* vo = cacheV + ((size_t)h * MCACHE + gm) * DHEAD + doff;
                const float4 n0 = *(const float4*)(vn);
                const float4 n1 = *(const float4*)(vn + 4);
                const float4 o0 = *(const float4*)(vo);
                const float4 o1 = *(const float4*)(vo + 4);
#pragma unroll
                for (int j = 0; j < 4; ++j) {
                    a[j][0] += pj[j] * (n0.x - o0.x); a[j][1] += pj[j] * (n0.y - o0.y);
                    a[j][2] += pj[j] * (n0.z - o0.z); a[j][3] += pj[j] * (n0.w - o0.w);
                    a[j][4] += pj[j] * (n1.x - o1.x); a[j][5] += pj[j] * (n1.y - o1.y);
                    a[j][6] += pj[j] * (n1.z - o1.z); a[j][7] += pj[j] * (n1.w - o1.w);
                }
            }
        }

        const size_t ob = ((size_t)h * NCHT + c) * S_LEN * DHEAD;
#pragma unroll
        for (int j = 0; j < 4; ++j) {
            const int s = sq * 4 + j;
            uint4 pk;
            unsigned short* us = (unsigned short*)&pk;
#pragma unroll
            for (int k = 0; k < 8; ++k) us[k] = f2h(a[j][k]);
            *(uint4*)&opart[ob + (size_t)s * DHEAD + doff] = pk;
        }
    }

    if (tid < 32) {
        const int w2 = tid >> 4, s = tid & 15;
        const int cc = bx * 2 + w2;
        mstat[((size_t)h * S_LEN + s) * NCHT + cc] = ml[w2][s];
        lstat[((size_t)h * S_LEN + s) * NCHT + cc] = ll[w2][s];
    }
}

// ---------------- Kernel 4: combine (coalesced d-pair loads) ----------------
__global__ __launch_bounds__(512) void attn_combine(const unsigned short* __restrict__ opart,
                                                    const float* __restrict__ mstat,
                                                    const float* __restrict__ lstat,
                                                    float* __restrict__ out) {
    const int tid = threadIdx.x;
    const int dp  = tid & 63;        // d-pair: d = 2*dp, 2*dp+1
    const int cg  = tid >> 6;        // 0..7
    const int s   = blockIdx.x;
    const int h   = blockIdx.y;

    __shared__ float mlds[NCHT], llds[NCHT], wlds[NCHT];
    __shared__ float olds[8][DHEAD];
    __shared__ float Llds[8];

    const size_t sb = ((size_t)h * S_LEN + s) * NCHT;
    if (tid < NCHT) { mlds[tid] = mstat[sb + tid]; llds[tid] = lstat[sb + tid]; }
    __syncthreads();

    float gmax = fmaxf(mlds[tid & 63], mlds[(tid & 63) + 64]);
    for (int off = 32; off > 0; off >>= 1) gmax = fmaxf(gmax, __shfl_xor(gmax, off, 64));

    if (tid < NCHT) wlds[tid] = __expf(mlds[tid] - gmax);
    __syncthreads();

    float ox = 0.f, oy = 0.f, L = 0.f;
    for (int c = cg; c < NCHT; c += 8) {
        const float w = wlds[c];
        const unsigned int u = *(const unsigned int*)
            &opart[(((size_t)h * NCHT + c) * S_LEN + s) * DHEAD + dp * 2];
        ox += w * h2f((unsigned short)(u & 0xffffu));
        oy += w * h2f((unsigned short)(u >> 16));
        L  += w * llds[c];
    }
    olds[cg][dp * 2]     = ox;
    olds[cg][dp * 2 + 1] = oy;
    if (dp == 0) Llds[cg] = L;
    __syncthreads();

    if (tid < DHEAD) {
        float ot = 0.f, Lt = 0.f;
#pragma unroll
        for (int g = 0; g < 8; ++g) { ot += olds[g][tid]; Lt += Llds[g]; }
        out[((size_t)h * S_LEN + s) * DHEAD + tid] = ot / Lt;
    }
}

extern "C" void kernel_launch(void* const* d_in, const int* in_sizes, int n_in,
                              void* d_out, int out_size, void* d_ws, size_t ws_size,
                              hipStream_t stream) {
    const float* X      = (const float*)d_in[0];
    const float* Wq     = (const float*)d_in[1];
    const float* Wk     = (const float*)d_in[2];
    const float* Wv     = (const float*)d_in[3];
    const float* cacheK = (const float*)d_in[4];
    const float* cacheV = (const float*)d_in[5];
    const int*   P      = (const int*)d_in[6];
    float* out = (float*)d_out;
    float* ws  = (float*)d_ws;

    float*          qkv   = ws;                                  // 196608 floats
    float*          part  = qkv + 3 * S_LEN * NMODEL;
    unsigned short* opart = (unsigned short*)part;               // aliases part
    float*          mstat = part + REGION_ELEMS;
    float*          lstat = mstat + STAT_ELEMS;

    qkv_gemm<<<dim3(8, SPLITK, 3), 256, 0, stream>>>(X, Wq, Wk, Wv, part);
    qkv_reduce<<<(3 * S_LEN * NMODEL / 4) / 256, 256, 0, stream>>>(part, qkv);
    attn_partial<<<dim3(NCHT / 2, HHEADS), 128, 0, stream>>>(qkv, cacheK, cacheV, P,
                                                             opart, mstat, lstat);
    attn_combine<<<dim3(S_LEN, HHEADS), 512, 0, stream>>>(opart, mstat, lstat, out);
}